// Round 6
// baseline (201.793 us; speedup 1.0000x reference)
//
#include <hip/hip_runtime.h>
#include <math.h>

// SO3 convolution lmax=2 — fully fused, 3 dispatches:
//   0) memsetAsync cnt[A]=0  (4.8 KB)
//   1) build_kernel: elist[a][pos]=e via cursor atomic (12000 threads, ~µs)
//   2) atom_kernel: 1200 blocks x 256 (4 waves). Wave w owns edges k=w,w+4,..
//      of its atom. Per edge (ALL inline, each edge processed exactly once):
//        - Y[9] from dir (uniform scalars), written to per-wave LDS
//        - M[s1][s3] built in per-wave LDS via ds atomics (CG entries hoisted
//          to registers outside the loop); wave-internal ordering only ->
//          __threadfence_block(), NO __syncthreads in the loop
//        - radial matvec against L1-resident Wf (30 KB), cutoff scale
//        - xj gather (9 float2/thread, coalesced), 9x9 contraction (pk-FMA)
//      4-wave LDS reduction, single coalesced store. No float atomics, no
//      Mall/Wij workspace round-trip.

#define S9     9
#define NF     128
#define NRAD   20
#define MAXDEG 64
#define MPAD   12        // padded M row stride

__device__ inline float2 f2fma(float a, float2 b, float2 c) {
    return make_float2(fmaf(a, b.x, c.x), fmaf(a, b.y, c.y));
}

// ---------------- kernel 1: edge-list build ----------------
__global__ void build_kernel(const int* __restrict__ idx_i, int E,
                             int* __restrict__ cnt, int* __restrict__ elist) {
    int e = blockIdx.x * blockDim.x + threadIdx.x;
    if (e < E) {
        int i = idx_i[e];
        int pos = atomicAdd(&cnt[i], 1);
        if (pos < MAXDEG) elist[i * MAXDEG + pos] = e;
    }
}

// ---------------- kernel 2: fused atom kernel ----------------
__global__ __launch_bounds__(256, 4) void atom_kernel(
    const float* __restrict__ x,        // [A, 9, 128]
    const float* __restrict__ radial,   // [E, 20]
    const float* __restrict__ dir,      // [E, 3]
    const float* __restrict__ cutoff,   // [E]
    const float* __restrict__ Wf,       // [20, 384]
    const float* __restrict__ bf,       // [384]
    const float* __restrict__ cg_vals,  // [ncg]
    const int* __restrict__ idx_j,      // [E]
    const int* __restrict__ cg_i1,
    const int* __restrict__ cg_i2,
    const int* __restrict__ cg_i3,
    int ncg,
    const int* __restrict__ cnt,        // [A]
    const int* __restrict__ elist,      // [A, MAXDEG]
    float* __restrict__ out)            // [A, 9, 128]
{
    const int a   = blockIdx.x;
    const int tid = threadIdx.x;
    const int w   = tid >> 6;           // wave 0..3
    const int t   = tid & 63;           // f-pair: f = 2t, 2t+1
    const int deg = min(cnt[a], MAXDEG);

    __shared__ float sacc[4][S9][NF];                   // 18 KB: per-wave partials
    __shared__ __align__(16) float Msh[4][S9 * MPAD];   // per-wave M, rows [s1][s3]
    __shared__ __align__(16) float Ysh[4][12];          // per-wave Y

    // hoist CG entries (edge-invariant) into registers: lane t owns entries t, t+64
    int  adr1 = 0, iy1 = 0, adr2 = 0, iy2 = 0;
    float cv1 = 0.f, cv2 = 0.f;
    const bool has1 = (t < ncg);
    const bool has2 = (t + 64 < ncg);
    if (has1) { adr1 = cg_i1[t] * MPAD + cg_i3[t];           iy1 = cg_i2[t];      cv1 = cg_vals[t]; }
    if (has2) { adr2 = cg_i1[t + 64] * MPAD + cg_i3[t + 64]; iy2 = cg_i2[t + 64]; cv2 = cg_vals[t + 64]; }
    const bool more = (ncg > 128);

    const float2 b0 = ((const float2*)(bf + 0 * NF))[t];
    const float2 b1 = ((const float2*)(bf + 1 * NF))[t];
    const float2 b2 = ((const float2*)(bf + 2 * NF))[t];

    float2 acc[S9];
    #pragma unroll
    for (int s = 0; s < S9; ++s) acc[s] = make_float2(0.f, 0.f);

    float* Mw = Msh[w];
    float* Yw = Ysh[w];

    for (int k = w; k < deg; k += 4) {
        const int e = __builtin_amdgcn_readfirstlane(elist[a * MAXDEG + k]);
        const int j = __builtin_amdgcn_readfirstlane(idx_j[e]);

        // zero M (54 lanes x float2 covers 108 floats)
        if (t < 54) ((float2*)Mw)[t] = make_float2(0.f, 0.f);

        // spherical harmonics (uniform values; lane 0 writes to LDS)
        {
            float dx = dir[3 * e], dy = dir[3 * e + 1], dz = dir[3 * e + 2];
            const float inv = rsqrtf(dx * dx + dy * dy + dz * dz);
            dx *= inv; dy *= inv; dz *= inv;
            const float s3c  = 1.7320508075688772f;   // sqrt(3)
            const float s5c  = 2.2360679774997896f;   // sqrt(5)
            const float s15c = 3.8729833462074170f;   // sqrt(15)
            if (t == 0) {
                *(float4*)&Yw[0] = make_float4(1.0f, s3c * dy, s3c * dz, s3c * dx);
                *(float4*)&Yw[4] = make_float4(s15c * dx * dy, s15c * dy * dz,
                                               0.5f * s5c * (3.0f * dz * dz - 1.0f),
                                               s15c * dx * dz);
                Yw[8] = 0.5f * s15c * (dx * dx - dy * dy);
            }
        }
        __threadfence_block();    // zero + Y visible to this wave's atomics

        // build M from hoisted CG entries
        if (has1) atomicAdd(&Mw[adr1], cv1 * Yw[iy1]);
        if (has2) atomicAdd(&Mw[adr2], cv2 * Yw[iy2]);
        if (more) {
            for (int kk = t + 128; kk < ncg; kk += 64)
                atomicAdd(&Mw[cg_i1[kk] * MPAD + cg_i3[kk]], cg_vals[kk] * Yw[cg_i2[kk]]);
        }
        __threadfence_block();    // atomics complete before row reads

        // radial filter inline: rad uniform -> scalar loads; Wf rows L1-hot
        const float cut = cutoff[e];
        float2 wl0 = b0, wl1 = b1, wl2 = b2;
        #pragma unroll
        for (int r = 0; r < NRAD; ++r) {
            const float rr = radial[e * NRAD + r];
            const float2* row = (const float2*)(Wf + r * (3 * NF));
            wl0 = f2fma(rr, row[t],       wl0);
            wl1 = f2fma(rr, row[t + 64],  wl1);
            wl2 = f2fma(rr, row[t + 128], wl2);
        }
        wl0.x *= cut; wl0.y *= cut;
        wl1.x *= cut; wl1.y *= cut;
        wl2.x *= cut; wl2.y *= cut;

        // neighbor features (coalesced float2)
        const float2* xp = (const float2*)(x + (size_t)j * (S9 * NF)) + t;
        float2 xj[S9];
        #pragma unroll
        for (int s = 0; s < S9; ++s) xj[s] = xp[s * 64];

        // ts[s3] = sum_s1 M[s1][s3] * xj[s1]  (row s1 read as f4,f4,f1 broadcast)
        float2 ts[S9];
        #pragma unroll
        for (int s = 0; s < S9; ++s) ts[s] = make_float2(0.f, 0.f);
        #pragma unroll
        for (int s1 = 0; s1 < S9; ++s1) {
            const float4 m0 = *(const float4*)&Mw[s1 * MPAD];
            const float4 m1 = *(const float4*)&Mw[s1 * MPAD + 4];
            const float  m8 = Mw[s1 * MPAD + 8];
            ts[0] = f2fma(m0.x, xj[s1], ts[0]);
            ts[1] = f2fma(m0.y, xj[s1], ts[1]);
            ts[2] = f2fma(m0.z, xj[s1], ts[2]);
            ts[3] = f2fma(m0.w, xj[s1], ts[3]);
            ts[4] = f2fma(m1.x, xj[s1], ts[4]);
            ts[5] = f2fma(m1.y, xj[s1], ts[5]);
            ts[6] = f2fma(m1.z, xj[s1], ts[6]);
            ts[7] = f2fma(m1.w, xj[s1], ts[7]);
            ts[8] = f2fma(m8,   xj[s1], ts[8]);
        }
        #pragma unroll
        for (int s3 = 0; s3 < S9; ++s3) {
            const float2 ww = (s3 == 0) ? wl0 : ((s3 < 4) ? wl1 : wl2);
            acc[s3].x = fmaf(ww.x, ts[s3].x, acc[s3].x);
            acc[s3].y = fmaf(ww.y, ts[s3].y, acc[s3].y);
        }
        __threadfence_block();    // row reads done before next iter zeroes M
    }

    // cross-wave reduction (uniform control flow: all waves reach here)
    #pragma unroll
    for (int s = 0; s < S9; ++s)
        *(float2*)&sacc[w][s][2 * t] = acc[s];
    __syncthreads();

    for (int idx = tid; idx < S9 * 64; idx += 256) {
        const int s  = idx >> 6;
        const int tp = idx & 63;
        float2 v0 = *(const float2*)&sacc[0][s][2 * tp];
        float2 v1 = *(const float2*)&sacc[1][s][2 * tp];
        float2 v2 = *(const float2*)&sacc[2][s][2 * tp];
        float2 v3 = *(const float2*)&sacc[3][s][2 * tp];
        float2 r = make_float2((v0.x + v1.x) + (v2.x + v3.x),
                               (v0.y + v1.y) + (v2.y + v3.y));
        *(float2*)&out[(size_t)a * (S9 * NF) + s * NF + 2 * tp] = r;
    }
}

extern "C" void kernel_launch(void* const* d_in, const int* in_sizes, int n_in,
                              void* d_out, int out_size, void* d_ws, size_t ws_size,
                              hipStream_t stream) {
    const float* x       = (const float*)d_in[0];
    const float* radial  = (const float*)d_in[1];
    const float* dir     = (const float*)d_in[2];
    const float* cutoff  = (const float*)d_in[3];
    const float* Wf      = (const float*)d_in[4];
    const float* bf      = (const float*)d_in[5];
    const float* cg_vals = (const float*)d_in[6];
    const int*   idx_i   = (const int*)d_in[7];
    const int*   idx_j   = (const int*)d_in[8];
    const int*   cg_i1   = (const int*)d_in[9];
    const int*   cg_i2   = (const int*)d_in[10];
    const int*   cg_i3   = (const int*)d_in[11];
    // d_in[12] = w_idx: unused (w_idx[k] == l(cg_idx_out[k]), folded into kernel)

    const int E   = in_sizes[7];
    const int ncg = in_sizes[6];
    const int A   = in_sizes[0] / (S9 * NF);

    // ws: cnt[A] | elist[A*MAXDEG]
    int* cnt   = (int*)d_ws;
    int* elist = cnt + A;

    hipMemsetAsync(cnt, 0, (size_t)A * sizeof(int), stream);

    build_kernel<<<(E + 255) / 256, 256, 0, stream>>>(idx_i, E, cnt, elist);

    atom_kernel<<<A, 256, 0, stream>>>(
        x, radial, dir, cutoff, Wf, bf, cg_vals,
        idx_j, cg_i1, cg_i2, cg_i3, ncg, cnt, elist, (float*)d_out);
}

// Round 7
// 163.374 us; speedup vs baseline: 1.2352x; 1.2352x over previous
//
#include <hip/hip_runtime.h>
#include <math.h>

// SO3 convolution lmax=2 — 3 dispatches:
//   0) memsetAsync cnt[A]=0
//   1) prep_kernel (E blocks x 64): per-edge Y -> M[s1][s3] built in LDS
//      (barriers OK here, once per edge), stored to Mall[e] (81 dwords);
//      per-atom edge list via cursor atomic. NO radial matvec here.
//   2) atom_kernel (A blocks x 256 = 4 waves): wave w owns edges w, w+4,...
//      Hot loop is FENCE-FREE (round-6 lesson: workgroup fences invalidate
//      vector L1 + force vmcnt(0) -> 133 MB refetch):
//        - M via uniform scalar loads from Mall (e is readfirstlane-uniform)
//        - radial matvec fused inline (Wf 30 KB stays L1-hot)
//        - xj gather (9 float2, coalesced), 81 pk-FMA contraction
//      4-wave LDS reduction at the end only; single coalesced store.
//      Plain __launch_bounds__(256): no VGPR cap -> no scratch spill.

#define S9      9
#define NF      128
#define NRAD    20
#define MAXDEG  64
#define MSTRIDE 96      // padded dwords per edge in Mall (81 used)

__device__ inline float2 f2fma(float a, float2 b, float2 c) {
    return make_float2(fmaf(a, b.x, c.x), fmaf(a, b.y, c.y));
}

// ---------------- kernel 1: per-edge prep ----------------
__global__ __launch_bounds__(64) void prep_kernel(
    const float* __restrict__ dir,      // [E, 3]
    const float* __restrict__ cg_vals,  // [ncg]
    const int* __restrict__ idx_i,      // [E]
    const int* __restrict__ cg_i1,
    const int* __restrict__ cg_i2,
    const int* __restrict__ cg_i3,
    int ncg,
    int* __restrict__ cnt,              // [A]
    int* __restrict__ elist,            // [A, MAXDEG]
    float* __restrict__ Mall)           // [E, MSTRIDE]  (transposed [s1][s3])
{
    const int e = blockIdx.x;
    const int t = threadIdx.x;

    __shared__ float Msh[81];
    __shared__ float Ysh[9];

    if (t < 81) Msh[t] = 0.0f;
    if (t + 64 < 81) Msh[t + 64] = 0.0f;

    if (t == 0) {
        float dx = dir[3 * e], dy = dir[3 * e + 1], dz = dir[3 * e + 2];
        const float inv = rsqrtf(dx * dx + dy * dy + dz * dz);
        dx *= inv; dy *= inv; dz *= inv;
        const float s3c  = 1.7320508075688772f;   // sqrt(3)
        const float s5c  = 2.2360679774997896f;   // sqrt(5)
        const float s15c = 3.8729833462074170f;   // sqrt(15)
        Ysh[0] = 1.0f;
        Ysh[1] = s3c * dy;
        Ysh[2] = s3c * dz;
        Ysh[3] = s3c * dx;
        Ysh[4] = s15c * dx * dy;
        Ysh[5] = s15c * dy * dz;
        Ysh[6] = 0.5f * s5c * (3.0f * dz * dz - 1.0f);
        Ysh[7] = s15c * dx * dz;
        Ysh[8] = 0.5f * s15c * (dx * dx - dy * dy);
        const int i = idx_i[e];
        const int pos = atomicAdd(&cnt[i], 1);
        if (pos < MAXDEG) elist[i * MAXDEG + pos] = e;
    }
    __syncthreads();

    // sparse CG -> M (transposed: slot = s1*9 + s3)
    for (int k = t; k < ncg; k += 64)
        atomicAdd(&Msh[cg_i1[k] * S9 + cg_i3[k]], cg_vals[k] * Ysh[cg_i2[k]]);
    __syncthreads();

    float* mp = Mall + (size_t)e * MSTRIDE;
    if (t < 81) mp[t] = Msh[t];
    if (t + 64 < 81) mp[t + 64] = Msh[t + 64];
}

// ---------------- kernel 2: 4 waves per atom, fence-free hot loop ----------------
__global__ __launch_bounds__(256) void atom_kernel(
    const float* __restrict__ x,        // [A, 9, 128]
    const float* __restrict__ radial,   // [E, 20]
    const float* __restrict__ cutoff,   // [E]
    const float* __restrict__ Wf,       // [20, 384]
    const float* __restrict__ bf,       // [384]
    const int* __restrict__ idx_j,      // [E]
    const int* __restrict__ cnt,        // [A]
    const int* __restrict__ elist,      // [A, MAXDEG]
    const float* __restrict__ Mall,     // [E, MSTRIDE]
    float* __restrict__ out)            // [A, 9, 128]
{
    const int a   = blockIdx.x;
    const int tid = threadIdx.x;
    const int w   = tid >> 6;           // wave 0..3
    const int t   = tid & 63;           // f-pair: f = 2t, 2t+1
    const int deg = min(cnt[a], MAXDEG);

    __shared__ float sacc[4][S9][NF];   // 18 KB per-wave partials

    const float2 b0 = ((const float2*)(bf + 0 * NF))[t];
    const float2 b1 = ((const float2*)(bf + 1 * NF))[t];
    const float2 b2 = ((const float2*)(bf + 2 * NF))[t];

    float2 acc[S9];
    #pragma unroll
    for (int s = 0; s < S9; ++s) acc[s] = make_float2(0.f, 0.f);

    // scalar prefetch pipeline: e/j for next iteration fetched before compute
    int k = w;
    int e_cur = 0, j_cur = 0;
    if (k < deg) {
        e_cur = __builtin_amdgcn_readfirstlane(elist[a * MAXDEG + k]);
        j_cur = __builtin_amdgcn_readfirstlane(idx_j[e_cur]);
    }
    while (k < deg) {
        const int kn = k + 4;
        int e_nx = 0, j_nx = 0;
        if (kn < deg) {
            e_nx = __builtin_amdgcn_readfirstlane(elist[a * MAXDEG + kn]);
            j_nx = __builtin_amdgcn_readfirstlane(idx_j[e_nx]);
        }

        // neighbor features first (longest-latency vector loads)
        const float2* xp = (const float2*)(x + (size_t)j_cur * (S9 * NF)) + t;
        float2 xj[S9];
        #pragma unroll
        for (int s = 0; s < S9; ++s) xj[s] = xp[s * 64];

        // radial matvec inline; radial/cutoff are uniform -> scalar loads,
        // Wf rows are block-wide shared -> L1 hits
        const float* rp = radial + (size_t)e_cur * NRAD;
        const float cut = cutoff[e_cur];
        float2 wl0 = b0, wl1 = b1, wl2 = b2;
        #pragma unroll
        for (int r = 0; r < NRAD; ++r) {
            const float rr = rp[r];
            const float2* row = (const float2*)(Wf + r * (3 * NF));
            wl0 = f2fma(rr, row[t],       wl0);
            wl1 = f2fma(rr, row[t + 64],  wl1);
            wl2 = f2fma(rr, row[t + 128], wl2);
        }
        wl0.x *= cut; wl0.y *= cut;
        wl1.x *= cut; wl1.y *= cut;
        wl2.x *= cut; wl2.y *= cut;

        // M contraction: Me uniform -> scalar loads (SMEM), broadcast to pk-FMA
        const float* Me = Mall + (size_t)e_cur * MSTRIDE;
        float2 ts[S9];
        #pragma unroll
        for (int s = 0; s < S9; ++s) ts[s] = make_float2(0.f, 0.f);
        #pragma unroll
        for (int s1 = 0; s1 < S9; ++s1) {
            #pragma unroll
            for (int s3 = 0; s3 < S9; ++s3)
                ts[s3] = f2fma(Me[s1 * S9 + s3], xj[s1], ts[s3]);
        }
        #pragma unroll
        for (int s3 = 0; s3 < S9; ++s3) {
            const float2 ww = (s3 == 0) ? wl0 : ((s3 < 4) ? wl1 : wl2);
            acc[s3].x = fmaf(ww.x, ts[s3].x, acc[s3].x);
            acc[s3].y = fmaf(ww.y, ts[s3].y, acc[s3].y);
        }

        k = kn; e_cur = e_nx; j_cur = j_nx;
    }

    // cross-wave reduction (single __syncthreads in the whole kernel)
    #pragma unroll
    for (int s = 0; s < S9; ++s)
        *(float2*)&sacc[w][s][2 * t] = acc[s];
    __syncthreads();

    for (int idx = tid; idx < S9 * 64; idx += 256) {
        const int s  = idx >> 6;
        const int tp = idx & 63;
        float2 v0 = *(const float2*)&sacc[0][s][2 * tp];
        float2 v1 = *(const float2*)&sacc[1][s][2 * tp];
        float2 v2 = *(const float2*)&sacc[2][s][2 * tp];
        float2 v3 = *(const float2*)&sacc[3][s][2 * tp];
        float2 r = make_float2((v0.x + v1.x) + (v2.x + v3.x),
                               (v0.y + v1.y) + (v2.y + v3.y));
        *(float2*)&out[(size_t)a * (S9 * NF) + s * NF + 2 * tp] = r;
    }
}

extern "C" void kernel_launch(void* const* d_in, const int* in_sizes, int n_in,
                              void* d_out, int out_size, void* d_ws, size_t ws_size,
                              hipStream_t stream) {
    const float* x       = (const float*)d_in[0];
    const float* radial  = (const float*)d_in[1];
    const float* dir     = (const float*)d_in[2];
    const float* cutoff  = (const float*)d_in[3];
    const float* Wf      = (const float*)d_in[4];
    const float* bf      = (const float*)d_in[5];
    const float* cg_vals = (const float*)d_in[6];
    const int*   idx_i   = (const int*)d_in[7];
    const int*   idx_j   = (const int*)d_in[8];
    const int*   cg_i1   = (const int*)d_in[9];
    const int*   cg_i2   = (const int*)d_in[10];
    const int*   cg_i3   = (const int*)d_in[11];
    // d_in[12] = w_idx: unused (w_idx[k] == l(cg_idx_out[k]), folded into kernel)

    const int E   = in_sizes[7];
    const int ncg = in_sizes[6];
    const int A   = in_sizes[0] / (S9 * NF);

    // ws: cnt[A] | elist[A*MAXDEG] | (align 512B) | Mall[E*MSTRIDE]
    int* cnt   = (int*)d_ws;
    int* elist = cnt + A;
    size_t off = ((size_t)(A + A * MAXDEG) * sizeof(int) + 511) & ~(size_t)511;
    float* Mall = (float*)((char*)d_ws + off);

    hipMemsetAsync(cnt, 0, (size_t)A * sizeof(int), stream);

    prep_kernel<<<E, 64, 0, stream>>>(
        dir, cg_vals, idx_i, cg_i1, cg_i2, cg_i3, ncg, cnt, elist, Mall);

    atom_kernel<<<A, 256, 0, stream>>>(
        x, radial, cutoff, Wf, bf, idx_j, cnt, elist, Mall, (float*)d_out);
}